// Round 28
// baseline (87.290 us; speedup 1.0000x reference)
//
#include <hip/hip_runtime.h>
#include <stdint.h>

#define BN_ 8192
#define DK_ 256
#define LOG2E 1.4426950408889634f
// int8 quantization: q = round(127*x); dot fits i32 exactly
#define INVQ (1.0f / 16129.0f)          // 1/127^2: acc -> natural-units sim
#define KQ   (LOG2E / 16129.0f)          // acc -> log2-units sim

typedef __attribute__((ext_vector_type(4))) float f32x4;
typedef __attribute__((ext_vector_type(4))) int i32x4;

// async global->LDS, 16B/lane; LDS dest wave-uniform base + lane*16, global src per-lane
#define GLD16(gp, lp)                                                   \
  __builtin_amdgcn_global_load_lds(                                     \
      (__attribute__((address_space(1))) void*)(gp),                    \
      (__attribute__((address_space(3))) void*)(lp), 16, 0, 0)

#define BAR() __builtin_amdgcn_s_barrier()
#define VM0() asm volatile("s_waitcnt vmcnt(0)" ::: "memory")

// ---------------- Kernel 1: row-normalize fp32 -> int8 (x127); also zeroes sumexp ----------------
__global__ __launch_bounds__(256) void norm_kernel(
    const float* __restrict__ hf, const float* __restrict__ lf,
    const float* __restrict__ af, unsigned char* __restrict__ qbase,
    float* __restrict__ sumexp) {
  const int tid = threadIdx.x;
  if (blockIdx.x < 16) {   // folded memset of sumexp[16384]
    f32x4 z = {0.f, 0.f, 0.f, 0.f};
    *(f32x4*)(sumexp + blockIdx.x * 1024 + tid * 4) = z;
  }
  const int w = tid >> 6, lane = tid & 63;
  const int grow = blockIdx.x * 4 + w;
  const int m = grow >> 13;
  const int r = grow & (BN_ - 1);
  const float* src = (m == 0) ? hf : (m == 1) ? lf : af;
  unsigned char* dst = qbase + (size_t)m * BN_ * DK_;
  const float4 v = ((const float4*)(src + (size_t)r * DK_))[lane];
  float ss = v.x * v.x + v.y * v.y + v.z * v.z + v.w * v.w;
#pragma unroll
  for (int mk = 32; mk >= 1; mk >>= 1) ss += __shfl_xor(ss, mk, 64);
  const float inv = 127.0f / fmaxf(sqrtf(ss), 1e-8f);
  const int q0 = (int)rintf(v.x * inv), q1 = (int)rintf(v.y * inv);
  const int q2 = (int)rintf(v.z * inv), q3 = (int)rintf(v.w * inv);
  const unsigned pk = (q0 & 255) | ((q1 & 255) << 8) | ((q2 & 255) << 16) |
                      ((unsigned)(q3 & 255) << 24);
  *(unsigned*)(dst + (size_t)r * DK_ + lane * 4) = pk;
}

// ---------------- Kernel 2: int8-GEMM, B direct global->reg + exp2-row-sum + diag ----------------
// Champion geometry (R19/R23: 256 blocks = 128 mt x 2 cg; 8 waves 2wr x 4wc;
// wave tile 64x64; 16x16x64 MFMA; A panel 32KB LDS, swizzled, single barrier)
// with the B-LDS ROUND-TRIP DELETED: B fragments load straight from global
// (an = 2MB, L2-resident, reused 128x) as plain IR loads. This removes per
// unit: 4 global_load_lds, 4 ds_reads, and the VM4 asm clobber -- the main
// loop has ZERO inline asm, so the compiler can software-pipeline the whole
// ct body (16 A-ds_reads + 16 B-gloads + 64 MFMAs, pure dataflow deps).
// A frags read per-unit from LDS (pipe now idle; keeps VGPR ~130 -- R25's
// allocator spills rather than exceed 128). No races: B is wave-private
// regs; A LDS read-only after the single barrier.
__global__ __launch_bounds__(512, 2) void gemm_lse_kernel(
    const unsigned char* __restrict__ hl, const unsigned char* __restrict__ an,
    float* __restrict__ sumexp /*[16384]*/, float* __restrict__ diag /*[16384]*/) {
  extern __shared__ char lds[];  // 32KB: A panel only

  const int tid = threadIdx.x;
  const int lane = tid & 63, w = tid >> 6;
  const int wr = w >> 2, wc = w & 3;
  const int lmod = lane & 15, lhalf = lane >> 4;

  const int bid = blockIdx.x;
  const int swz = (bid & 7) * 32 + (bid >> 3);  // bijective on 256, XCD-grouping
  const int mt = swz >> 1;                      // row panel 0..127 (128 rows each)
  const int cg = swz & 1;                       // col half (16 ct of 256 cols)

  // ---- A cooperative stage: [128 rows][16 slots], phys16 = s ^ (row&15) ----
  const int aswz = 16 * ((tid & 15) ^ ((tid >> 4) & 15));
  const unsigned char* aG = hl + (size_t)(mt * 128 + (tid >> 4)) * DK_ + aswz;
  char* aD = lds + tid * 16;
  GLD16(aG, aD);
  GLD16(aG + 8192, aD + 8192);
  GLD16(aG + 16384, aD + 16384);
  GLD16(aG + 24576, aD + 24576);
  VM0();   // all 4 A loads retired
  BAR();   // A collectively resident (the kernel's only barrier)

  const char* aR = lds + (wr * 64 + lmod) * 256;   // A row base (verified formula)

  // ---- B global base: row = cg*4096 + wc*64 + (n*16 + lmod), k = lhalf*16 ----
  const unsigned char* bG =
      an + (size_t)(cg * 4096 + wc * 64 + lmod) * DK_ + lhalf * 16;

  // ---- diag geometry (champion-verified) ----
  const int p = mt >> 6;
  const int D = (mt & 63) * 128 + wr * 64;
  const bool dWave = (wc == ((D >> 6) & 3)) && ((D >> 12) == cg);
  const int ctD = (D >> 8) & 15;

  float rsum[4][4];
#pragma unroll
  for (int m = 0; m < 4; ++m)
#pragma unroll
    for (int r = 0; r < 4; ++r) rsum[m][r] = 0.0f;

#pragma unroll 1
  for (int ct = 0; ct < 16; ++ct) {
    i32x4 acc[4][4];
#pragma unroll
    for (int m = 0; m < 4; ++m)
#pragma unroll
      for (int n = 0; n < 4; ++n) acc[m][n] = i32x4{0, 0, 0, 0};

    const unsigned char* bCt = bG + (size_t)ct * 65536;   // ct*256 rows
#pragma unroll
    for (int ku = 0; ku < 4; ++ku) {
      i32x4 af[4], bf[4];
#pragma unroll
      for (int n = 0; n < 4; ++n)
        bf[n] = *(const i32x4*)(bCt + n * 4096 + ku * 64);   // global (L2)
#pragma unroll
      for (int m = 0; m < 4; ++m)
        af[m] = *(const i32x4*)(aR + m * 4096 + 16 * ((ku * 4 + lhalf) ^ lmod));
#pragma unroll
      for (int m = 0; m < 4; ++m)
#pragma unroll
        for (int n = 0; n < 4; ++n)
          acc[m][n] = __builtin_amdgcn_mfma_i32_16x16x64_i8(af[m], bf[n], acc[m][n], 0, 0, 0);
    }

    // ---- tile epilogue: diag (rare, compile-time indices) + exp2 ----
    if (dWave && ct == ctD) {
#pragma unroll
      for (int m = 0; m < 4; ++m)
#pragma unroll
        for (int r = 0; r < 4; ++r)
          if (lmod == lhalf * 4 + r)
            diag[p * BN_ + D + m * 16 + lmod] = (float)acc[m][m][r] * INVQ;
    }
#pragma unroll
    for (int m = 0; m < 4; ++m)
#pragma unroll
      for (int n = 0; n < 4; ++n)
#pragma unroll
        for (int r = 0; r < 4; ++r)
          rsum[m][r] += __builtin_amdgcn_exp2f((float)acc[m][n][r] * KQ);
  }

  // ---- final: reduce across 16 col-lanes, then atomicAdd ----
#pragma unroll
  for (int m = 0; m < 4; ++m)
#pragma unroll
    for (int r = 0; r < 4; ++r) {
      float v = rsum[m][r];
      v += __shfl_xor(v, 1, 64);
      v += __shfl_xor(v, 2, 64);
      v += __shfl_xor(v, 4, 64);
      v += __shfl_xor(v, 8, 64);
      if (lmod == 0)
        atomicAdd(&sumexp[p * BN_ + D + m * 16 + lhalf * 4 + r], v);
    }
}

// ---------------- Kernel 3: CE = mean(log(sumexp) - diag) ----------------
__global__ __launch_bounds__(1024) void finalize_kernel(
    const float* __restrict__ sumexp, const float* __restrict__ diag,
    float* __restrict__ out) {
  const int tid = threadIdx.x;
  float s = 0.0f;
  for (int i = tid; i < 2 * BN_; i += 1024) s += logf(sumexp[i]) - diag[i];
#pragma unroll
  for (int mk = 32; mk >= 1; mk >>= 1) s += __shfl_xor(s, mk, 64);
  __shared__ float red[16];
  if ((tid & 63) == 0) red[tid >> 6] = s;
  __syncthreads();
  if (tid == 0) {
    float t = 0.f;
#pragma unroll
    for (int j = 0; j < 16; ++j) t += red[j];
    out[0] = t * (1.0f / (float)BN_);
  }
}

extern "C" void kernel_launch(void* const* d_in, const int* in_sizes, int n_in,
                              void* d_out, int out_size, void* d_ws, size_t ws_size,
                              hipStream_t stream) {
  const float* hf = (const float*)d_in[0];
  const float* lf = (const float*)d_in[1];
  const float* af = (const float*)d_in[2];

  char* ws = (char*)d_ws;
  const size_t nmat = (size_t)BN_ * DK_;                 // 2MB as i8
  unsigned char* qbase = (unsigned char*)ws;             // hq(2MB) lq(2MB) aq(2MB)
  unsigned char* hl = qbase;                             // stacked A [16384][256]
  unsigned char* an = qbase + 2 * nmat;
  float* sumexp = (float*)(ws + 3 * nmat);               // 64 KB [16384]
  float* diag = sumexp + 2 * BN_;                        // 64 KB [16384]

  hipFuncSetAttribute((const void*)gemm_lse_kernel,
                      hipFuncAttributeMaxDynamicSharedMemorySize, 32768);

  norm_kernel<<<(3 * BN_) / 4, 256, 0, stream>>>(hf, lf, af, qbase, sumexp);
  gemm_lse_kernel<<<256, 512, 32768, stream>>>(hl, an, sumexp, diag);
  finalize_kernel<<<1, 1024, 0, stream>>>(sumexp, diag, (float*)d_out);
}

// Round 29
// 65.021 us; speedup vs baseline: 1.3425x; 1.3425x over previous
//
#include <hip/hip_runtime.h>
#include <stdint.h>

#define BN_ 8192
#define DK_ 256
#define LOG2E 1.4426950408889634f
// int8 quantization: q = round(127*x); dot fits i32 exactly
#define INVQ (1.0f / 16129.0f)          // 1/127^2: acc -> natural-units sim
#define KQ   (LOG2E / 16129.0f)          // acc -> log2-units sim

typedef __attribute__((ext_vector_type(4))) float f32x4;
typedef __attribute__((ext_vector_type(4))) int i32x4;

// async global->LDS, 16B/lane; LDS dest wave-uniform base + lane*16, global src per-lane
#define GLD16(gp, lp)                                                   \
  __builtin_amdgcn_global_load_lds(                                     \
      (__attribute__((address_space(1))) void*)(gp),                    \
      (__attribute__((address_space(3))) void*)(lp), 16, 0, 0)

#define BAR() __builtin_amdgcn_s_barrier()
#define VM4() asm volatile("s_waitcnt vmcnt(4)" ::: "memory")
#define VM0() asm volatile("s_waitcnt vmcnt(0)" ::: "memory")

// ---------------- Kernel 1: row-normalize fp32 -> int8 (x127); also zeroes sumexp ----------------
__global__ __launch_bounds__(256) void norm_kernel(
    const float* __restrict__ hf, const float* __restrict__ lf,
    const float* __restrict__ af, unsigned char* __restrict__ qbase,
    float* __restrict__ sumexp) {
  const int tid = threadIdx.x;
  if (blockIdx.x < 16) {   // folded memset of sumexp[16384]
    f32x4 z = {0.f, 0.f, 0.f, 0.f};
    *(f32x4*)(sumexp + blockIdx.x * 1024 + tid * 4) = z;
  }
  const int w = tid >> 6, lane = tid & 63;
  const int grow = blockIdx.x * 4 + w;
  const int m = grow >> 13;
  const int r = grow & (BN_ - 1);
  const float* src = (m == 0) ? hf : (m == 1) ? lf : af;
  unsigned char* dst = qbase + (size_t)m * BN_ * DK_;
  const float4 v = ((const float4*)(src + (size_t)r * DK_))[lane];
  float ss = v.x * v.x + v.y * v.y + v.z * v.z + v.w * v.w;
#pragma unroll
  for (int mk = 32; mk >= 1; mk >>= 1) ss += __shfl_xor(ss, mk, 64);
  const float inv = 127.0f / fmaxf(sqrtf(ss), 1e-8f);
  const int q0 = (int)rintf(v.x * inv), q1 = (int)rintf(v.y * inv);
  const int q2 = (int)rintf(v.z * inv), q3 = (int)rintf(v.w * inv);
  const unsigned pk = (q0 & 255) | ((q1 & 255) << 8) | ((q2 & 255) << 16) |
                      ((unsigned)(q3 & 255) << 24);
  *(unsigned*)(dst + (size_t)r * DK_ + lane * 4) = pk;
}

// ---------------- Kernel 2: barrier-free int8-GEMM + exp2-row-sum + diag ----------------
// FINAL FORM (R19/R23/R26 champion, reproduced at 52.2-53.4us gemm):
// A = [hq;lq] stacked [16384,256] i8, B = aq [8192,256] i8, S = A·B^T.
// 256 blocks = 128 mt x 2 cg; 8 waves (2wr x 4wc), wave tile 64x64.
// A panel (128x256B = 32KB) staged once (the kernel's ONLY barrier), A frags
// hoisted to registers (afr[4][4]). Each wave double-buffers a PRIVATE 4KB B
// slice in its own LDS region: RAW gated by the wave's own vmcnt(4)
// (in-order VMEM retirement), WAR by program order. Zero main-loop barriers
// -> waves de-phase naturally (m114 overlap).
// A/B'd-and-rejected on this op: setprio (R23 null), reg-dbuf prefetch (R22
// null), 32x32 MFMA (R27 worse: B-read bank conflicts + lower MfmaUtil),
// direct-global B (R28 worse: L2 latency on critical path), occupancy via
// smaller blocks/LDS (R12/R13/R21/R24 null -- occupancy counter immovable),
// epilogue ping-pong (R25 spills at the 128-reg allocator cliff), window
// reorder/stagger (R15/R17 worse). Residual ~50% issue-idle at 2 waves/SIMD
// is intra-wave dependency latency -- hand-asm interleave regime, not
// reachable at HIP source on this structure.
__global__ __launch_bounds__(512, 2) void gemm_lse_kernel(
    const unsigned char* __restrict__ hl, const unsigned char* __restrict__ an,
    float* __restrict__ sumexp /*[16384]*/, float* __restrict__ diag /*[16384]*/) {
  extern __shared__ char lds[];  // 96KB: A 32KB + 8 waves x 8KB B

  const int tid = threadIdx.x;
  const int lane = tid & 63, w = tid >> 6;
  const int wr = w >> 2, wc = w & 3;
  const int lmod = lane & 15, lhalf = lane >> 4;

  const int bid = blockIdx.x;
  const int swz = (bid & 7) * 32 + (bid >> 3);  // bijective on 256, XCD-grouping
  const int mt = swz >> 1;                      // row panel 0..127 (128 rows each)
  const int cg = swz & 1;                       // col half (16 ct of 256 cols)

  // ---- A cooperative stage: [128 rows][16 slots], phys16 = s ^ (row&15) ----
  const int aswz = 16 * ((tid & 15) ^ ((tid >> 4) & 15));
  const unsigned char* aG = hl + (size_t)(mt * 128 + (tid >> 4)) * DK_ + aswz;
  char* aD = lds + tid * 16;
  GLD16(aG, aD);
  GLD16(aG + 8192, aD + 8192);
  GLD16(aG + 16384, aD + 16384);
  GLD16(aG + 24576, aD + 24576);

  // ---- B private staging constants (R16/R19-verified 64-row slice layout) ----
  const int slog16 = 16 * ((lane & 3) ^ ((lane >> 3) & 3));
  const unsigned char* bB =
      an + (size_t)(cg * 4096 + wc * 64 + (lane >> 2)) * DK_ + slog16;
  char* ldsB = lds + 32768 + w * 8192 + lane * 16;

#define STAGEB(uu)                                                       \
  do {                                                                   \
    const int ct_ = (uu) >> 2, ku_ = (uu) & 3;                           \
    const unsigned char* g_ = bB + ct_ * 65536 + ku_ * 64;               \
    char* d_ = ldsB + ((uu) & 1) * 4096;                                 \
    GLD16(g_, d_);                                                       \
    GLD16(g_ + 4096, d_ + 1024);                                         \
    GLD16(g_ + 8192, d_ + 2048);                                         \
    GLD16(g_ + 12288, d_ + 3072);                                        \
  } while (0)

  STAGEB(0);
  VM4();   // 8 outstanding (4 A + 4 B0) -> <=4 left: A drained (B0 flies)
  BAR();   // the kernel's ONLY barrier: A collectively resident

  // ---- hoist all A fragments: afr[ku][m], row = wr*64+m*16+lmod,
  //      byte = row*256 + 16*((ku*4+lhalf) ^ (row&15)),  row&15 == lmod
  i32x4 afr[4][4];
  {
    const char* aR = lds + (wr * 64 + lmod) * 256;
#pragma unroll
    for (int ku = 0; ku < 4; ++ku)
#pragma unroll
      for (int m = 0; m < 4; ++m)
        afr[ku][m] = *(const i32x4*)(aR + m * 4096 + 16 * ((ku * 4 + lhalf) ^ lmod));
  }

  const int rdoffB = lmod * 64 + 16 * (lhalf ^ ((lmod >> 1) & 3));
  const char* ldsBr = lds + 32768 + w * 8192;

  // ---- diag geometry: D = 64-aligned col block equal to this wave's row block ----
  const int p = mt >> 6;
  const int D = (mt & 63) * 128 + wr * 64;
  const bool dWave = (wc == ((D >> 6) & 3)) && ((D >> 12) == cg);
  const int ctD = (D >> 8) & 15;

  float rsum[4][4];
#pragma unroll
  for (int m = 0; m < 4; ++m)
#pragma unroll
    for (int r = 0; r < 4; ++r) rsum[m][r] = 0.0f;

#pragma unroll 1
  for (int ct = 0; ct < 16; ++ct) {
    i32x4 acc[4][4];
#pragma unroll
    for (int m = 0; m < 4; ++m)
#pragma unroll
      for (int n = 0; n < 4; ++n) acc[m][n] = i32x4{0, 0, 0, 0};

#pragma unroll
    for (int ku = 0; ku < 4; ++ku) {
      const int u = ct * 4 + ku;
      if (u < 63) {
        STAGEB(u + 1);
        VM4();   // my B(u) landed (only B(u+1)'s 4 loads may remain)
      } else {
        VM0();   // last unit: drain B(63)
      }
      const char* Lb = ldsBr + (u & 1) * 4096;
      i32x4 bf[4];
#pragma unroll
      for (int n = 0; n < 4; ++n) bf[n] = *(const i32x4*)(Lb + n * 1024 + rdoffB);
#pragma unroll
      for (int m = 0; m < 4; ++m)
#pragma unroll
        for (int n = 0; n < 4; ++n)
          acc[m][n] = __builtin_amdgcn_mfma_i32_16x16x64_i8(afr[ku][m], bf[n], acc[m][n], 0, 0, 0);
    }

    // ---- tile epilogue: diag (rare, compile-time indices) + exp2 ----
    if (dWave && ct == ctD) {
#pragma unroll
      for (int m = 0; m < 4; ++m)
#pragma unroll
        for (int r = 0; r < 4; ++r)
          if (lmod == lhalf * 4 + r)
            diag[p * BN_ + D + m * 16 + lmod] = (float)acc[m][m][r] * INVQ;
    }
#pragma unroll
    for (int m = 0; m < 4; ++m)
#pragma unroll
      for (int n = 0; n < 4; ++n)
#pragma unroll
        for (int r = 0; r < 4; ++r)
          rsum[m][r] += __builtin_amdgcn_exp2f((float)acc[m][n][r] * KQ);
  }

  // ---- final: reduce across 16 col-lanes, then atomicAdd ----
#pragma unroll
  for (int m = 0; m < 4; ++m)
#pragma unroll
    for (int r = 0; r < 4; ++r) {
      float v = rsum[m][r];
      v += __shfl_xor(v, 1, 64);
      v += __shfl_xor(v, 2, 64);
      v += __shfl_xor(v, 4, 64);
      v += __shfl_xor(v, 8, 64);
      if (lmod == 0)
        atomicAdd(&sumexp[p * BN_ + D + m * 16 + lhalf * 4 + r], v);
    }
#undef STAGEB
}

// ---------------- Kernel 3: CE = mean(log(sumexp) - diag) ----------------
__global__ __launch_bounds__(1024) void finalize_kernel(
    const float* __restrict__ sumexp, const float* __restrict__ diag,
    float* __restrict__ out) {
  const int tid = threadIdx.x;
  float s = 0.0f;
  for (int i = tid; i < 2 * BN_; i += 1024) s += logf(sumexp[i]) - diag[i];
#pragma unroll
  for (int mk = 32; mk >= 1; mk >>= 1) s += __shfl_xor(s, mk, 64);
  __shared__ float red[16];
  if ((tid & 63) == 0) red[tid >> 6] = s;
  __syncthreads();
  if (tid == 0) {
    float t = 0.f;
#pragma unroll
    for (int j = 0; j < 16; ++j) t += red[j];
    out[0] = t * (1.0f / (float)BN_);
  }
}

extern "C" void kernel_launch(void* const* d_in, const int* in_sizes, int n_in,
                              void* d_out, int out_size, void* d_ws, size_t ws_size,
                              hipStream_t stream) {
  const float* hf = (const float*)d_in[0];
  const float* lf = (const float*)d_in[1];
  const float* af = (const float*)d_in[2];

  char* ws = (char*)d_ws;
  const size_t nmat = (size_t)BN_ * DK_;                 // 2MB as i8
  unsigned char* qbase = (unsigned char*)ws;             // hq(2MB) lq(2MB) aq(2MB)
  unsigned char* hl = qbase;                             // stacked A [16384][256]
  unsigned char* an = qbase + 2 * nmat;
  float* sumexp = (float*)(ws + 3 * nmat);               // 64 KB [16384]
  float* diag = sumexp + 2 * BN_;                        // 64 KB [16384]

  hipFuncSetAttribute((const void*)gemm_lse_kernel,
                      hipFuncAttributeMaxDynamicSharedMemorySize, 98304);

  norm_kernel<<<(3 * BN_) / 4, 256, 0, stream>>>(hf, lf, af, qbase, sumexp);
  gemm_lse_kernel<<<256, 512, 98304, stream>>>(hl, an, sumexp, diag);
  finalize_kernel<<<1, 1024, 0, stream>>>(sumexp, diag, (float*)d_out);
}